// Round 2
// baseline (1260.089 us; speedup 1.0000x reference)
//
#include <hip/hip_runtime.h>
#include <math.h>

#define NC 32
#define NI 32
#define NL 50
#define NQ 36
#define ND 1024
#define LAMBDA 9.0f

#define BM 128
#define BN 128
#define BK 32
#define LDT 40  // LDS row stride (bf16 elems): 32 + 8 pad

typedef __attribute__((ext_vector_type(8))) short bf16x8;
typedef __attribute__((ext_vector_type(4))) float floatx4;

static __device__ __forceinline__ unsigned short f2b(float f) {
    unsigned int u = __float_as_uint(f);
    unsigned int r = (u + 0x7fffu + ((u >> 16) & 1u)) >> 16;  // RNE
    return (unsigned short)r;
}
static __device__ __forceinline__ float bf2f_lo(unsigned int u) {
    return __uint_as_float(u << 16);
}
static __device__ __forceinline__ float bf2f_hi(unsigned int u) {
    return __uint_as_float(u & 0xffff0000u);
}

// ---------------------------------------------------------------------------
// K0: fp32 -> bf16 conversion, 5 arrays in one launch (grid.y = job id)
// ---------------------------------------------------------------------------
struct CvtJob { const float* src; unsigned short* dst; int n2; };  // n2 = n/2
struct CvtJobs { CvtJob j[5]; };

__global__ __launch_bounds__(256) void k_cvt(CvtJobs jobs) {
    CvtJob jb = jobs.j[blockIdx.y];
    unsigned int* d32 = (unsigned int*)jb.dst;
    int stride = gridDim.x * 256;
    for (int i = blockIdx.x * 256 + threadIdx.x; i < jb.n2; i += stride) {
        float2 v = ((const float2*)jb.src)[i];
        d32[i] = (unsigned int)f2b(v.x) | ((unsigned int)f2b(v.y) << 16);
    }
}

// ---------------------------------------------------------------------------
// K1: s[c,i,l,q] = normalize_q( leaky( wrd[c,l,:] . rgn[i,q,:] ) )  [fp32]
// block per (c,i,l); 256 threads = 4 waves; wave w handles q = w, w+4, ...
// ---------------------------------------------------------------------------
__global__ __launch_bounds__(256) void k_scores(
    const float* __restrict__ rgn, const float* __restrict__ wrd,
    const int* __restrict__ lens, float* __restrict__ sbuf)
{
    int bid = blockIdx.x;
    int c = bid / (NI * NL);
    int rem = bid % (NI * NL);
    int i = rem / NL, l = rem % NL;
    if (l >= lens[c]) return;  // attn for invalid words is exactly 0 downstream

    __shared__ float wrow[ND];
    __shared__ float sq[NQ];
    __shared__ float s_inv;
    int t = threadIdx.x;
    ((float4*)wrow)[t] = ((const float4*)(wrd + (size_t)(c * NL + l) * ND))[t];
    __syncthreads();

    int lane = t & 63, wid = t >> 6;
    for (int q = wid; q < NQ; q += 4) {
        const float* r = rgn + (size_t)(i * NQ + q) * ND;
        float acc = 0.f;
#pragma unroll
        for (int j = 0; j < 16; ++j) acc += r[lane + 64 * j] * wrow[lane + 64 * j];
#pragma unroll
        for (int off = 32; off; off >>= 1) acc += __shfl_down(acc, off);
        if (lane == 0) sq[q] = acc >= 0.f ? acc : 0.1f * acc;
    }
    __syncthreads();
    if (t < 64) {
        float v = (t < NQ) ? sq[t] : 0.f;
        float ss = v * v;
#pragma unroll
        for (int off = 32; off; off >>= 1) ss += __shfl_down(ss, off);
        if (t == 0) s_inv = 1.f / fmaxf(sqrtf(ss), 1e-12f);
    }
    __syncthreads();
    if (t < NQ) sbuf[((size_t)(c * NI + i) * NL + l) * NQ + t] = sq[t] * s_inv;
}

// ---------------------------------------------------------------------------
// K2: masked softmax over l (per c,i,q). Wave per item, lane = l. In-place.
// ---------------------------------------------------------------------------
__global__ __launch_bounds__(256) void k_softmax(
    const int* __restrict__ lens, float* __restrict__ sbuf)
{
    int t = threadIdx.x, lane = t & 63, wid = t >> 6;
    int item = blockIdx.x * 4 + wid;  // < NC*NI*NQ
    int c = item / (NI * NQ);
    int rem = item % (NI * NQ);
    int i = rem / NQ, q = rem % NQ;
    int len = lens[c];
    float* base = sbuf + ((size_t)(c * NI + i) * NL) * NQ + q;
    float v = -1e30f;
    if (lane < len) v = base[(size_t)lane * NQ] * LAMBDA;
    float m = v;
#pragma unroll
    for (int off = 32; off; off >>= 1) m = fmaxf(m, __shfl_xor(m, off));
    float p = (lane < len) ? __expf(v - m) : 0.f;
    float s = p;
#pragma unroll
    for (int off = 32; off; off >>= 1) s += __shfl_xor(s, off);
    float a = p / s;
    if (lane < NL) base[(size_t)lane * NQ] = a;
}

// ---------------------------------------------------------------------------
// K3: wei[(c,i,q), d] = sum_l attn[c,i,l,q] * wrd_bf[c,l,d]   (bf16 out)
// block per (c,i,q); thread covers 4 d via two uint (2x bf16) loads.
// ---------------------------------------------------------------------------
__global__ __launch_bounds__(256) void k_wei(
    const unsigned short* __restrict__ wrd_bf, const float* __restrict__ sbuf,
    unsigned short* __restrict__ wei)
{
    int item = blockIdx.x;
    int c = item / (NI * NQ);
    int rem = item % (NI * NQ);
    int i = rem / NQ, q = rem % NQ;
    __shared__ float al[NL];
    int t = threadIdx.x;
    if (t < NL) al[t] = sbuf[((size_t)(c * NI + i) * NL + t) * NQ + q];
    __syncthreads();
    float a0 = 0.f, a1 = 0.f, a2 = 0.f, a3 = 0.f;
    const unsigned int* w32 = (const unsigned int*)(wrd_bf + (size_t)c * NL * ND);
    for (int l = 0; l < NL; ++l) {
        float a = al[l];          // uniform across block
        if (a == 0.f) continue;   // invalid words contribute nothing
        const unsigned int* row = w32 + l * (ND / 2);
        unsigned int x0 = row[t], x1 = row[t + 256];
        a0 += a * bf2f_lo(x0); a1 += a * bf2f_hi(x0);
        a2 += a * bf2f_lo(x1); a3 += a * bf2f_hi(x1);
    }
    unsigned int* o32 = (unsigned int*)(wei + (size_t)item * ND);
    o32[t]       = (unsigned int)f2b(a0) | ((unsigned int)f2b(a1) << 16);
    o32[t + 256] = (unsigned int)f2b(a2) | ((unsigned int)f2b(a3) << 16);
}

// ---------------------------------------------------------------------------
// MFMA GEMM: D(M x N) = A(M x K) . B(N x K)^T with fused epilogues.
// MODE 0: dual-B;  x_bf16 = rgn*tanh(A.B1^T + b1) + (A.B2^T + b2)
// MODE 1: h_bf16 = relu(A.B1^T + b1)
// MODE 2: out_f32[(i,c,q),n] = A.B1^T + b1 + rgn   (c<->i permuted store)
// Block: 256 thr = 4 waves (2x2), 128x128 tile, BK=32, 16x16x32 MFMA, 4x4/wave
// ---------------------------------------------------------------------------
template <int MODE, int MINW>
__global__ __launch_bounds__(256, MINW) void k_gemm(
    const unsigned short* __restrict__ A, const unsigned short* __restrict__ B1,
    const unsigned short* __restrict__ B2, const float* __restrict__ bias1,
    const float* __restrict__ bias2, const float* __restrict__ rgnf,
    void* __restrict__ outp)
{
    const int K = ND;
    int bn = blockIdx.x, bm = blockIdx.y;
    int m0 = bm * BM, n0 = bn * BN;

    __shared__ __align__(16) unsigned short At[BM * LDT];
    __shared__ __align__(16) unsigned short Bt[BN * LDT];
    __shared__ __align__(16) unsigned short Bt2[MODE == 0 ? BN * LDT : 16];

    int t = threadIdx.x;
    int lane = t & 63, wid = t >> 6;
    int wx = wid & 1, wy = wid >> 1;
    int lrow = lane & 15, quad = lane >> 4;

    floatx4 acc[4][4] = {};
    floatx4 acc2[MODE == 0 ? 4 : 1][MODE == 0 ? 4 : 1] = {};

    int srow = t >> 2;            // 0..63
    int scol = (t & 3) * 8;       // 0,8,16,24 (k elems)
    const unsigned short* Aptr  = A  + (size_t)(m0 + srow) * K + scol;
    const unsigned short* B1ptr = B1 + (size_t)(n0 + srow) * K + scol;

    for (int kt = 0; kt < K; kt += BK) {
        *(uint4*)&At[srow * LDT + scol]        = *(const uint4*)(Aptr + kt);
        *(uint4*)&At[(srow + 64) * LDT + scol] = *(const uint4*)(Aptr + (size_t)64 * K + kt);
        *(uint4*)&Bt[srow * LDT + scol]        = *(const uint4*)(B1ptr + kt);
        *(uint4*)&Bt[(srow + 64) * LDT + scol] = *(const uint4*)(B1ptr + (size_t)64 * K + kt);
        if constexpr (MODE == 0) {
            const unsigned short* B2ptr = B2 + (size_t)(n0 + srow) * K + scol;
            *(uint4*)&Bt2[srow * LDT + scol]        = *(const uint4*)(B2ptr + kt);
            *(uint4*)&Bt2[(srow + 64) * LDT + scol] = *(const uint4*)(B2ptr + (size_t)64 * K + kt);
        }
        __syncthreads();

        bf16x8 af[4], bfr[4];
#pragma unroll
        for (int im = 0; im < 4; ++im)
            af[im] = *(const bf16x8*)&At[(wy * 64 + im * 16 + lrow) * LDT + quad * 8];
#pragma unroll
        for (int in = 0; in < 4; ++in)
            bfr[in] = *(const bf16x8*)&Bt[(wx * 64 + in * 16 + lrow) * LDT + quad * 8];
#pragma unroll
        for (int im = 0; im < 4; ++im)
#pragma unroll
            for (int in = 0; in < 4; ++in)
                acc[im][in] = __builtin_amdgcn_mfma_f32_16x16x32_bf16(
                    af[im], bfr[in], acc[im][in], 0, 0, 0);
        if constexpr (MODE == 0) {
            bf16x8 bfr2[4];
#pragma unroll
            for (int in = 0; in < 4; ++in)
                bfr2[in] = *(const bf16x8*)&Bt2[(wx * 64 + in * 16 + lrow) * LDT + quad * 8];
#pragma unroll
            for (int im = 0; im < 4; ++im)
#pragma unroll
                for (int in = 0; in < 4; ++in)
                    acc2[im][in] = __builtin_amdgcn_mfma_f32_16x16x32_bf16(
                        af[im], bfr2[in], acc2[im][in], 0, 0, 0);
        }
        __syncthreads();
    }

    // epilogue: C/D layout col = lane&15, row = quad*4 + reg  [m89/m91]
#pragma unroll
    for (int im = 0; im < 4; ++im) {
#pragma unroll
        for (int in = 0; in < 4; ++in) {
            int n = n0 + wx * 64 + in * 16 + lrow;
            float b1v = bias1[n];
            float b2v = (MODE == 0) ? bias2[n] : 0.f;
#pragma unroll
            for (int r = 0; r < 4; ++r) {
                int m = m0 + wy * 64 + im * 16 + quad * 4 + r;
                int q = m % NQ;
                int ci = m / NQ;
                int i = ci % NI, c = ci / NI;
                float v = acc[im][in][r];
                if constexpr (MODE == 0) {
                    float sc = tanhf(v + b1v);
                    float sh = acc2[im][in][r] + b2v;
                    float rg = rgnf[(size_t)(i * NQ + q) * ND + n];
                    ((unsigned short*)outp)[(size_t)m * ND + n] = f2b(rg * sc + sh);
                } else if constexpr (MODE == 1) {
                    float h = v + b1v;
                    ((unsigned short*)outp)[(size_t)m * ND + n] = f2b(h > 0.f ? h : 0.f);
                } else {
                    float rg = rgnf[(size_t)(i * NQ + q) * ND + n];
                    ((float*)outp)[((size_t)(i * NC + c) * NQ + q) * ND + n] = v + b1v + rg;
                }
            }
        }
    }
}

extern "C" void kernel_launch(void* const* d_in, const int* in_sizes, int n_in,
                              void* d_out, int out_size, void* d_ws, size_t ws_size,
                              hipStream_t stream) {
    const float* rgn     = (const float*)d_in[0];
    const float* wrd     = (const float*)d_in[2];
    const int*   lens    = (const int*)d_in[4];
    const float* w_scale = (const float*)d_in[5];
    const float* b_scale = (const float*)d_in[6];
    const float* w_shift = (const float*)d_in[7];
    const float* b_shift = (const float*)d_in[8];
    const float* w1      = (const float*)d_in[9];
    const float* b1      = (const float*)d_in[10];
    const float* w2      = (const float*)d_in[11];
    const float* b2      = (const float*)d_in[12];
    float* outf = (float*)d_out;

    // workspace layout (bytes, all 16-aligned):
    char* ws = (char*)d_ws;
    float*          sbuf   = (float*)ws;                                  // 7,372,800
    unsigned short* wrd_bf = (unsigned short*)(ws + 7372800);             // 3,276,800
    unsigned short* wsc_bf = (unsigned short*)(ws + 10649600);            // 2,097,152
    unsigned short* wsh_bf = (unsigned short*)(ws + 12746752);            // 2,097,152
    unsigned short* w1_bf  = (unsigned short*)(ws + 14843904);            // 2,097,152
    unsigned short* w2_bf  = (unsigned short*)(ws + 16941056);            // 2,097,152
    unsigned short* wei    = (unsigned short*)(ws + 19038208);            // 75,497,472
    unsigned short* hbuf   = wei;                    // reuse: wei dead after gemm<0>
    unsigned short* xbuf   = (unsigned short*)d_out; // bf16 x inside fp32 out buffer;
                                                     // dead before gemm<2> overwrites

    CvtJobs jobs;
    jobs.j[0] = { wrd,     wrd_bf, NC * NL * ND / 2 };
    jobs.j[1] = { w_scale, wsc_bf, ND * ND / 2 };
    jobs.j[2] = { w_shift, wsh_bf, ND * ND / 2 };
    jobs.j[3] = { w1,      w1_bf,  ND * ND / 2 };
    jobs.j[4] = { w2,      w2_bf,  ND * ND / 2 };
    k_cvt<<<dim3(256, 5), 256, 0, stream>>>(jobs);

    k_scores<<<NC * NI * NL, 256, 0, stream>>>(rgn, wrd, lens, sbuf);
    k_softmax<<<(NC * NI * NQ) / 4, 256, 0, stream>>>(lens, sbuf);
    k_wei<<<NC * NI * NQ, 256, 0, stream>>>(wrd_bf, sbuf, wei);

    dim3 g(ND / BN, (NC * NI * NQ) / BM);  // 8 x 288
    k_gemm<0, 1><<<g, 256, 0, stream>>>(wei, wsc_bf, wsh_bf, b_scale, b_shift, rgn, xbuf);
    k_gemm<1, 2><<<g, 256, 0, stream>>>(xbuf, w1_bf, nullptr, b1, nullptr, rgn, hbuf);
    k_gemm<2, 2><<<g, 256, 0, stream>>>(hbuf, w2_bf, nullptr, b2, nullptr, rgn, outf);
}

// Round 3
// 1024.086 us; speedup vs baseline: 1.2305x; 1.2305x over previous
//
#include <hip/hip_runtime.h>
#include <math.h>

#define NC 32
#define NI 32
#define NL 50
#define NQ 36
#define ND 1024
#define LAMBDA 9.0f

#define BM 128
#define BN 128
#define BK 32
// LDS tile layout is UNPADDED (LDT=32): required by global_load_lds
// (wave-uniform base + lane*16), and conflict-free for our fragment reads
// (per-wave ds_read_b128 addresses permute a contiguous 1KB region).

typedef __attribute__((ext_vector_type(8))) short bf16x8;
typedef __attribute__((ext_vector_type(4))) float floatx4;

static __device__ __forceinline__ unsigned short f2b(float f) {
    unsigned int u = __float_as_uint(f);
    unsigned int r = (u + 0x7fffu + ((u >> 16) & 1u)) >> 16;  // RNE
    return (unsigned short)r;
}
static __device__ __forceinline__ float bf2f_lo(unsigned int u) {
    return __uint_as_float(u << 16);
}
static __device__ __forceinline__ float bf2f_hi(unsigned int u) {
    return __uint_as_float(u & 0xffff0000u);
}

// async global->LDS, 16B per lane; LDS dest must be uniform base + lane*16
static __device__ __forceinline__ void gload16(const unsigned short* g, unsigned short* l) {
    __builtin_amdgcn_global_load_lds(
        (const __attribute__((address_space(1))) unsigned int*)g,
        (__attribute__((address_space(3))) unsigned int*)l, 16, 0, 0);
}

// ---------------------------------------------------------------------------
// K0: fp32 -> bf16 conversion, 5 arrays in one launch (grid.y = job id)
// ---------------------------------------------------------------------------
struct CvtJob { const float* src; unsigned short* dst; int n2; };  // n2 = n/2
struct CvtJobs { CvtJob j[5]; };

__global__ __launch_bounds__(256) void k_cvt(CvtJobs jobs) {
    CvtJob jb = jobs.j[blockIdx.y];
    unsigned int* d32 = (unsigned int*)jb.dst;
    int stride = gridDim.x * 256;
    for (int i = blockIdx.x * 256 + threadIdx.x; i < jb.n2; i += stride) {
        float2 v = ((const float2*)jb.src)[i];
        d32[i] = (unsigned int)f2b(v.x) | ((unsigned int)f2b(v.y) << 16);
    }
}

// ---------------------------------------------------------------------------
// K1: s[c,i,l,q] = normalize_q( leaky( wrd[c,l,:] . rgn[i,q,:] ) )  [fp32]
// block per (c,i,l); 256 threads = 4 waves; wave w handles q = w, w+4, ...
// ---------------------------------------------------------------------------
__global__ __launch_bounds__(256) void k_scores(
    const float* __restrict__ rgn, const float* __restrict__ wrd,
    const int* __restrict__ lens, float* __restrict__ sbuf)
{
    int bid = blockIdx.x;
    int c = bid / (NI * NL);
    int rem = bid % (NI * NL);
    int i = rem / NL, l = rem % NL;
    if (l >= lens[c]) return;  // attn for invalid words is exactly 0 downstream

    __shared__ float wrow[ND];
    __shared__ float sq[NQ];
    __shared__ float s_inv;
    int t = threadIdx.x;
    ((float4*)wrow)[t] = ((const float4*)(wrd + (size_t)(c * NL + l) * ND))[t];
    __syncthreads();

    int lane = t & 63, wid = t >> 6;
    for (int q = wid; q < NQ; q += 4) {
        const float* r = rgn + (size_t)(i * NQ + q) * ND;
        float acc = 0.f;
#pragma unroll
        for (int j = 0; j < 16; ++j) acc += r[lane + 64 * j] * wrow[lane + 64 * j];
#pragma unroll
        for (int off = 32; off; off >>= 1) acc += __shfl_down(acc, off);
        if (lane == 0) sq[q] = acc >= 0.f ? acc : 0.1f * acc;
    }
    __syncthreads();
    if (t < 64) {
        float v = (t < NQ) ? sq[t] : 0.f;
        float ss = v * v;
#pragma unroll
        for (int off = 32; off; off >>= 1) ss += __shfl_down(ss, off);
        if (t == 0) s_inv = 1.f / fmaxf(sqrtf(ss), 1e-12f);
    }
    __syncthreads();
    if (t < NQ) sbuf[((size_t)(c * NI + i) * NL + l) * NQ + t] = sq[t] * s_inv;
}

// ---------------------------------------------------------------------------
// K2: masked softmax over l (per c,i,q). Wave per item, lane = l. In-place.
// ---------------------------------------------------------------------------
__global__ __launch_bounds__(256) void k_softmax(
    const int* __restrict__ lens, float* __restrict__ sbuf)
{
    int t = threadIdx.x, lane = t & 63, wid = t >> 6;
    int item = blockIdx.x * 4 + wid;  // < NC*NI*NQ
    int c = item / (NI * NQ);
    int rem = item % (NI * NQ);
    int i = rem / NQ, q = rem % NQ;
    int len = lens[c];
    float* base = sbuf + ((size_t)(c * NI + i) * NL) * NQ + q;
    float v = -1e30f;
    if (lane < len) v = base[(size_t)lane * NQ] * LAMBDA;
    float m = v;
#pragma unroll
    for (int off = 32; off; off >>= 1) m = fmaxf(m, __shfl_xor(m, off));
    float p = (lane < len) ? __expf(v - m) : 0.f;
    float s = p;
#pragma unroll
    for (int off = 32; off; off >>= 1) s += __shfl_xor(s, off);
    float a = p / s;
    if (lane < NL) base[(size_t)lane * NQ] = a;
}

// ---------------------------------------------------------------------------
// K3: wei[(c,i,q), d] = sum_l attn[c,i,l,q] * wrd_bf[c,l,d]   (bf16 out)
// block per (c,i,q); thread covers 4 d via two uint (2x bf16) loads.
// ---------------------------------------------------------------------------
__global__ __launch_bounds__(256) void k_wei(
    const unsigned short* __restrict__ wrd_bf, const float* __restrict__ sbuf,
    unsigned short* __restrict__ wei)
{
    int item = blockIdx.x;
    int c = item / (NI * NQ);
    int rem = item % (NI * NQ);
    int i = rem / NQ, q = rem % NQ;
    __shared__ float al[NL];
    int t = threadIdx.x;
    if (t < NL) al[t] = sbuf[((size_t)(c * NI + i) * NL + t) * NQ + q];
    __syncthreads();
    float a0 = 0.f, a1 = 0.f, a2 = 0.f, a3 = 0.f;
    const unsigned int* w32 = (const unsigned int*)(wrd_bf + (size_t)c * NL * ND);
    for (int l = 0; l < NL; ++l) {
        float a = al[l];          // uniform across block
        if (a == 0.f) continue;   // invalid words contribute nothing
        const unsigned int* row = w32 + l * (ND / 2);
        unsigned int x0 = row[t], x1 = row[t + 256];
        a0 += a * bf2f_lo(x0); a1 += a * bf2f_hi(x0);
        a2 += a * bf2f_lo(x1); a3 += a * bf2f_hi(x1);
    }
    unsigned int* o32 = (unsigned int*)(wei + (size_t)item * ND);
    o32[t]       = (unsigned int)f2b(a0) | ((unsigned int)f2b(a1) << 16);
    o32[t + 256] = (unsigned int)f2b(a2) | ((unsigned int)f2b(a3) << 16);
}

// ---------------------------------------------------------------------------
// MFMA GEMM: D(M x N) = A(M x K) . B(N x K)^T with fused epilogues.
// MODE 0: dual-B;  x_bf16 = rgn*tanh(A.B1^T + b1) + (A.B2^T + b2)
// MODE 1: h_bf16 = relu(A.B1^T + b1)
// MODE 2: out_f32[(i,c,q),n] = A.B1^T + b1 + rgn   (c<->i permuted store)
// Block: 256 thr = 4 waves (2x2), 128x128 tile, BK=32, 16x16x32 MFMA, 4x4/wave
// Staging: global_load_lds width=16, unpadded LDS (lane-linear layout).
// ---------------------------------------------------------------------------
template <int MODE, int MINW>
__global__ __launch_bounds__(256, MINW) void k_gemm(
    const unsigned short* __restrict__ A, const unsigned short* __restrict__ B1,
    const unsigned short* __restrict__ B2, const float* __restrict__ bias1,
    const float* __restrict__ bias2, const float* __restrict__ rgnf,
    void* __restrict__ outp)
{
    const int K = ND;
    int bn = blockIdx.x, bm = blockIdx.y;
    int m0 = bm * BM, n0 = bn * BN;

    __shared__ __align__(16) unsigned short At[BM * BK];
    __shared__ __align__(16) unsigned short Bt[BN * BK];
    __shared__ __align__(16) unsigned short Bt2[MODE == 0 ? BN * BK : 16];

    int t = threadIdx.x;
    int lane = t & 63, wid = t >> 6;
    int wx = wid & 1, wy = wid >> 1;
    int lrow = lane & 15, quad = lane >> 4;

    floatx4 acc[4][4] = {};
    floatx4 acc2[MODE == 0 ? 4 : 1][MODE == 0 ? 4 : 1] = {};

    int srow = t >> 2;            // 0..63
    int scol = (t & 3) * 8;       // 0,8,16,24 (k elems)
    const unsigned short* Aptr  = A  + (size_t)(m0 + srow) * K + scol;
    const unsigned short* B1ptr = B1 + (size_t)(n0 + srow) * K + scol;
    const unsigned short* B2ptr = (MODE == 0) ? B2 + (size_t)(n0 + srow) * K + scol : nullptr;
    unsigned short* Al = &At[srow * BK + scol];          // == wid*512 + lane*8 elems
    unsigned short* Al2 = &At[(srow + 64) * BK + scol];
    unsigned short* Bl = &Bt[srow * BK + scol];
    unsigned short* Bl2 = &Bt[(srow + 64) * BK + scol];

    for (int kt = 0; kt < K; kt += BK) {
        gload16(Aptr + kt, Al);
        gload16(Aptr + (size_t)64 * K + kt, Al2);
        gload16(B1ptr + kt, Bl);
        gload16(B1ptr + (size_t)64 * K + kt, Bl2);
        if constexpr (MODE == 0) {
            gload16(B2ptr + kt, &Bt2[srow * BK + scol]);
            gload16(B2ptr + (size_t)64 * K + kt, &Bt2[(srow + 64) * BK + scol]);
        }
        __syncthreads();  // drains vmcnt (global_load_lds) before reads

        bf16x8 af[4], bfr[4];
#pragma unroll
        for (int im = 0; im < 4; ++im)
            af[im] = *(const bf16x8*)&At[(wy * 64 + im * 16 + lrow) * BK + quad * 8];
#pragma unroll
        for (int in = 0; in < 4; ++in)
            bfr[in] = *(const bf16x8*)&Bt[(wx * 64 + in * 16 + lrow) * BK + quad * 8];
#pragma unroll
        for (int im = 0; im < 4; ++im)
#pragma unroll
            for (int in = 0; in < 4; ++in)
                acc[im][in] = __builtin_amdgcn_mfma_f32_16x16x32_bf16(
                    af[im], bfr[in], acc[im][in], 0, 0, 0);
        if constexpr (MODE == 0) {
            bf16x8 bfr2[4];
#pragma unroll
            for (int in = 0; in < 4; ++in)
                bfr2[in] = *(const bf16x8*)&Bt2[(wx * 64 + in * 16 + lrow) * BK + quad * 8];
#pragma unroll
            for (int im = 0; im < 4; ++im)
#pragma unroll
                for (int in = 0; in < 4; ++in)
                    acc2[im][in] = __builtin_amdgcn_mfma_f32_16x16x32_bf16(
                        af[im], bfr2[in], acc2[im][in], 0, 0, 0);
        }
        __syncthreads();
    }

    // epilogue: C/D layout col = lane&15, row = quad*4 + reg  [m89/m91]
#pragma unroll
    for (int im = 0; im < 4; ++im) {
#pragma unroll
        for (int in = 0; in < 4; ++in) {
            int n = n0 + wx * 64 + in * 16 + lrow;
            float b1v = bias1[n];
            float b2v = (MODE == 0) ? bias2[n] : 0.f;
#pragma unroll
            for (int r = 0; r < 4; ++r) {
                int m = m0 + wy * 64 + im * 16 + quad * 4 + r;
                int q = m % NQ;
                int ci = m / NQ;
                int i = ci % NI, c = ci / NI;
                float v = acc[im][in][r];
                if constexpr (MODE == 0) {
                    float sc = tanhf(v + b1v);
                    float sh = acc2[im][in][r] + b2v;
                    float rg = rgnf[(size_t)(i * NQ + q) * ND + n];
                    ((unsigned short*)outp)[(size_t)m * ND + n] = f2b(rg * sc + sh);
                } else if constexpr (MODE == 1) {
                    float h = v + b1v;
                    ((unsigned short*)outp)[(size_t)m * ND + n] = f2b(h > 0.f ? h : 0.f);
                } else {
                    float rg = rgnf[(size_t)(i * NQ + q) * ND + n];
                    ((float*)outp)[((size_t)(i * NC + c) * NQ + q) * ND + n] = v + b1v + rg;
                }
            }
        }
    }
}

extern "C" void kernel_launch(void* const* d_in, const int* in_sizes, int n_in,
                              void* d_out, int out_size, void* d_ws, size_t ws_size,
                              hipStream_t stream) {
    const float* rgn     = (const float*)d_in[0];
    const float* wrd     = (const float*)d_in[2];
    const int*   lens    = (const int*)d_in[4];
    const float* w_scale = (const float*)d_in[5];
    const float* b_scale = (const float*)d_in[6];
    const float* w_shift = (const float*)d_in[7];
    const float* b_shift = (const float*)d_in[8];
    const float* w1      = (const float*)d_in[9];
    const float* b1      = (const float*)d_in[10];
    const float* w2      = (const float*)d_in[11];
    const float* b2      = (const float*)d_in[12];
    float* outf = (float*)d_out;

    // workspace layout (bytes, all 16-aligned):
    char* ws = (char*)d_ws;
    float*          sbuf   = (float*)ws;                                  // 7,372,800
    unsigned short* wrd_bf = (unsigned short*)(ws + 7372800);             // 3,276,800
    unsigned short* wsc_bf = (unsigned short*)(ws + 10649600);            // 2,097,152
    unsigned short* wsh_bf = (unsigned short*)(ws + 12746752);            // 2,097,152
    unsigned short* w1_bf  = (unsigned short*)(ws + 14843904);            // 2,097,152
    unsigned short* w2_bf  = (unsigned short*)(ws + 16941056);            // 2,097,152
    unsigned short* wei    = (unsigned short*)(ws + 19038208);            // 75,497,472
    unsigned short* hbuf   = wei;                    // reuse: wei dead after gemm<0>
    unsigned short* xbuf   = (unsigned short*)d_out; // bf16 x inside fp32 out buffer;
                                                     // dead before gemm<2> overwrites

    CvtJobs jobs;
    jobs.j[0] = { wrd,     wrd_bf, NC * NL * ND / 2 };
    jobs.j[1] = { w_scale, wsc_bf, ND * ND / 2 };
    jobs.j[2] = { w_shift, wsh_bf, ND * ND / 2 };
    jobs.j[3] = { w1,      w1_bf,  ND * ND / 2 };
    jobs.j[4] = { w2,      w2_bf,  ND * ND / 2 };
    k_cvt<<<dim3(256, 5), 256, 0, stream>>>(jobs);

    k_scores<<<NC * NI * NL, 256, 0, stream>>>(rgn, wrd, lens, sbuf);
    k_softmax<<<(NC * NI * NQ) / 4, 256, 0, stream>>>(lens, sbuf);
    k_wei<<<NC * NI * NQ, 256, 0, stream>>>(wrd_bf, sbuf, wei);

    dim3 g(ND / BN, (NC * NI * NQ) / BM);  // 8 x 288
    k_gemm<0, 2><<<g, 256, 0, stream>>>(wei, wsc_bf, wsh_bf, b_scale, b_shift, rgn, xbuf);
    k_gemm<1, 2><<<g, 256, 0, stream>>>(xbuf, w1_bf, nullptr, b1, nullptr, rgn, hbuf);
    k_gemm<2, 2><<<g, 256, 0, stream>>>(hbuf, w2_bf, nullptr, b2, nullptr, rgn, outf);
}

// Round 4
// 714.505 us; speedup vs baseline: 1.7636x; 1.4333x over previous
//
#include <hip/hip_runtime.h>
#include <math.h>

#define NC 32
#define NI 32
#define NL 50
#define NQ 36
#define ND 1024
#define LAMBDA 9.0f

#define BM 128
#define BN 128
#define BK 32

typedef __attribute__((ext_vector_type(8))) short bf16x8;
typedef __attribute__((ext_vector_type(4))) float floatx4;

static __device__ __forceinline__ unsigned short f2b(float f) {
    unsigned int u = __float_as_uint(f);
    unsigned int r = (u + 0x7fffu + ((u >> 16) & 1u)) >> 16;  // RNE
    return (unsigned short)r;
}
static __device__ __forceinline__ float bf2f(unsigned short u) {
    return __uint_as_float(((unsigned int)u) << 16);
}

// async global->LDS, 16B/lane; LDS dest must be wave-uniform base + lane*16
static __device__ __forceinline__ void gload16(const unsigned short* g, unsigned short* l) {
    __builtin_amdgcn_global_load_lds(
        (const __attribute__((address_space(1))) unsigned int*)g,
        (__attribute__((address_space(3))) unsigned int*)l, 16, 0, 0);
}

// ---------------------------------------------------------------------------
// K0a: fp32 -> bf16 (4 weight matrices)
// ---------------------------------------------------------------------------
struct CvtJob { const float* src; unsigned short* dst; int n2; };
struct CvtJobs { CvtJob j[4]; };

__global__ __launch_bounds__(256) void k_cvt(CvtJobs jobs) {
    CvtJob jb = jobs.j[blockIdx.y];
    unsigned int* d32 = (unsigned int*)jb.dst;
    int stride = gridDim.x * 256;
    for (int i = blockIdx.x * 256 + threadIdx.x; i < jb.n2; i += stride) {
        float2 v = ((const float2*)jb.src)[i];
        d32[i] = (unsigned int)f2b(v.x) | ((unsigned int)f2b(v.y) << 16);
    }
}

// ---------------------------------------------------------------------------
// K0b: fp32 -> bf16 hi/lo split (x ~= hi + lo, lo = bf16(x - hi))
// ---------------------------------------------------------------------------
struct HlJob { const float* src; unsigned short* hi; unsigned short* lo; int n2; };
struct HlJobs { HlJob j[2]; };

__global__ __launch_bounds__(256) void k_cvt_hilo(HlJobs jobs) {
    HlJob jb = jobs.j[blockIdx.y];
    unsigned int* h32 = (unsigned int*)jb.hi;
    unsigned int* l32 = (unsigned int*)jb.lo;
    int stride = gridDim.x * 256;
    for (int i = blockIdx.x * 256 + threadIdx.x; i < jb.n2; i += stride) {
        float2 v = ((const float2*)jb.src)[i];
        unsigned short h0 = f2b(v.x), h1 = f2b(v.y);
        unsigned short l0 = f2b(v.x - bf2f(h0)), l1 = f2b(v.y - bf2f(h1));
        h32[i] = (unsigned int)h0 | ((unsigned int)h1 << 16);
        l32[i] = (unsigned int)l0 | ((unsigned int)l1 << 16);
    }
}

// ---------------------------------------------------------------------------
// K0c: wrd (c,l,d) fp32 -> wrd_t (c,d,l64) bf16, l padded to 64 with zeros
// ---------------------------------------------------------------------------
__global__ __launch_bounds__(256) void k_cvt_t(
    const float* __restrict__ wrd, unsigned short* __restrict__ wrdt)
{
    int c = blockIdx.y;
    int d = blockIdx.x * 256 + threadIdx.x;
    const float* src = wrd + (size_t)c * NL * ND + d;
    unsigned int o[32];
#pragma unroll
    for (int j = 0; j < 25; ++j) {
        float a = src[(size_t)(2 * j) * ND], b = src[(size_t)(2 * j + 1) * ND];
        o[j] = (unsigned int)f2b(a) | ((unsigned int)f2b(b) << 16);
    }
#pragma unroll
    for (int j = 25; j < 32; ++j) o[j] = 0;
    uint4* dst = (uint4*)(wrdt + ((size_t)c * ND + d) * 64);
#pragma unroll
    for (int j = 0; j < 8; ++j) dst[j] = ((uint4*)o)[j];
}

// ---------------------------------------------------------------------------
// K1: fused scores+normalize+softmax. Block per (c,i).
// S = leaky(W.R^T) via bf16 hi/lo MFMA (fp32-class precision), L2-norm over q,
// masked softmax over l -> attn bf16 [c][i][q][l64] (zeros for l>=len).
// M = 64 (50 words padded), N = 48 (36 q padded), K = 1024.
// ---------------------------------------------------------------------------
#define SST 37  // S LDS col stride

__global__ __launch_bounds__(256) void k_attn(
    const unsigned short* __restrict__ whi, const unsigned short* __restrict__ wlo,
    const unsigned short* __restrict__ rhi, const unsigned short* __restrict__ rlo,
    const int* __restrict__ lens, unsigned short* __restrict__ attn)
{
    int bx = blockIdx.x;
    int c = bx / NI, i = bx % NI;
    __shared__ __align__(16) unsigned short Wh[64 * 32], Wl[64 * 32];
    __shared__ __align__(16) unsigned short Rh[48 * 32], Rl[48 * 32];
    __shared__ float S[64 * SST];
    int t = threadIdx.x, lane = t & 63, wid = t >> 6;
    int lrow = lane & 15, quad = lane >> 4;
    int len = lens[c];

    // staging: wave0->Wh, wave1->Wl, wave2->Rh, wave3->Rl
    int grow = lane >> 2;                         // row within 16-row group
    int ssw = ((lane & 3) ^ ((lane >> 3) & 3)) * 8;  // swizzled source chunk
    const unsigned short* garr = (wid == 0) ? whi : (wid == 1) ? wlo : (wid == 2) ? rhi : rlo;
    unsigned short* larr = (wid == 0) ? Wh : (wid == 1) ? Wl : (wid == 2) ? Rh : Rl;
    int ngroups = (wid < 2) ? 4 : 3;
    size_t gbase = (wid < 2) ? (size_t)(c * NL) * ND : (size_t)(i * NQ) * ND;

    floatx4 acc[3] = {};
    int fsw = (quad ^ ((lrow >> 1) & 3)) * 8;

    for (int kt = 0; kt < ND; kt += 32) {
        for (int j = 0; j < ngroups; ++j) {
            int row = j * 16 + grow;
            gload16(garr + gbase + (size_t)row * ND + kt + ssw, larr + j * 512 + lane * 8);
        }
        __syncthreads();
        bf16x8 ah = *(const bf16x8*)&Wh[(wid * 16 + lrow) * 32 + fsw];
        bf16x8 al = *(const bf16x8*)&Wl[(wid * 16 + lrow) * 32 + fsw];
#pragma unroll
        for (int nt = 0; nt < 3; ++nt) {
            bf16x8 bh = *(const bf16x8*)&Rh[(nt * 16 + lrow) * 32 + fsw];
            bf16x8 bl = *(const bf16x8*)&Rl[(nt * 16 + lrow) * 32 + fsw];
            acc[nt] = __builtin_amdgcn_mfma_f32_16x16x32_bf16(ah, bh, acc[nt], 0, 0, 0);
            acc[nt] = __builtin_amdgcn_mfma_f32_16x16x32_bf16(ah, bl, acc[nt], 0, 0, 0);
            acc[nt] = __builtin_amdgcn_mfma_f32_16x16x32_bf16(al, bh, acc[nt], 0, 0, 0);
        }
        __syncthreads();
    }
    // scatter to S: l = wid*16 + quad*4 + r, q = nt*16 + lrow
#pragma unroll
    for (int nt = 0; nt < 3; ++nt) {
        int q = nt * 16 + lrow;
        if (q < NQ) {
#pragma unroll
            for (int r = 0; r < 4; ++r) {
                int l = wid * 16 + quad * 4 + r;
                S[l * SST + q] = acc[nt][r];
            }
        }
    }
    __syncthreads();
    // leaky + L2-normalize over q, times lambda -> logits
    if (t < NL) {
        float lv[NQ];
        float ss = 0.f;
#pragma unroll
        for (int q = 0; q < NQ; ++q) {
            float v = S[t * SST + q];
            float x = (v >= 0.f) ? v : 0.1f * v;
            lv[q] = x;
            ss += x * x;
        }
        float inv = LAMBDA / fmaxf(sqrtf(ss), 1e-12f);
#pragma unroll
        for (int q = 0; q < NQ; ++q) S[t * SST + q] = lv[q] * inv;
    }
    __syncthreads();
    // masked softmax over l, emit attn bf16 [c][i][q][64]
    if (t < NQ) {
        int q = t;
        float m = -1e30f;
        for (int l = 0; l < len; ++l) m = fmaxf(m, S[l * SST + q]);
        float sum = 0.f;
        for (int l = 0; l < len; ++l) {
            float p = __expf(S[l * SST + q] - m);
            S[l * SST + q] = p;
            sum += p;
        }
        float inv = 1.f / sum;
        unsigned int* o = (unsigned int*)attn + ((size_t)(c * NI + i) * NQ + q) * 32;
        for (int j = 0; j < 32; ++j) {
            int l0 = 2 * j, l1 = 2 * j + 1;
            unsigned short a0 = (l0 < len) ? f2b(S[l0 * SST + q] * inv) : (unsigned short)0;
            unsigned short a1 = (l1 < len) ? f2b(S[l1 * SST + q] * inv) : (unsigned short)0;
            o[j] = (unsigned int)a0 | ((unsigned int)a1 << 16);
        }
    }
}

// ---------------------------------------------------------------------------
// K2: wei[(c,m),d] = sum_l attn[c,m,l] * wrd_t[c,d,l]  as MFMA GEMM, K=64.
// Rows are 128B (8 chunks): swizzle pos = chunk ^ (row&7).
// ---------------------------------------------------------------------------
__global__ __launch_bounds__(256, 2) void k_wei_gemm(
    const unsigned short* __restrict__ attn, const unsigned short* __restrict__ wrdt,
    unsigned short* __restrict__ wei)
{
    int bn = blockIdx.x, bmt = blockIdx.y, c = blockIdx.z;
    __shared__ __align__(16) unsigned short At[128 * 64], Bt[128 * 64];
    int t = threadIdx.x, lane = t & 63, wid = t >> 6;
    int wx = wid & 1, wy = wid >> 1;
    int lrow = lane & 15, quad = lane >> 4;
    int grow = lane >> 3, pos = lane & 7;

    const unsigned short* Abase = attn + (size_t)(c * 1152 + bmt * 128) * 64;
    const unsigned short* Bbase = wrdt + (size_t)(c * 1024 + bn * 128) * 64;
    for (int g = wid; g < 16; g += 4) {
        int row = g * 8 + grow;
        int ssw = (pos ^ (row & 7)) * 8;
        gload16(Abase + (size_t)row * 64 + ssw, &At[g * 512 + lane * 8]);
        gload16(Bbase + (size_t)row * 64 + ssw, &Bt[g * 512 + lane * 8]);
    }
    __syncthreads();

    floatx4 acc[4][4] = {};
#pragma unroll
    for (int kk = 0; kk < 2; ++kk) {
        int sw = ((kk * 4 + quad) ^ (lrow & 7)) * 8;
        bf16x8 af[4], bf[4];
#pragma unroll
        for (int im = 0; im < 4; ++im)
            af[im] = *(const bf16x8*)&At[(wy * 64 + im * 16 + lrow) * 64 + sw];
#pragma unroll
        for (int in = 0; in < 4; ++in)
            bf[in] = *(const bf16x8*)&Bt[(wx * 64 + in * 16 + lrow) * 64 + sw];
#pragma unroll
        for (int im = 0; im < 4; ++im)
#pragma unroll
            for (int in = 0; in < 4; ++in)
                acc[im][in] = __builtin_amdgcn_mfma_f32_16x16x32_bf16(
                    af[im], bf[in], acc[im][in], 0, 0, 0);
    }
#pragma unroll
    for (int im = 0; im < 4; ++im)
#pragma unroll
        for (int in = 0; in < 4; ++in) {
            int d = bn * 128 + wx * 64 + in * 16 + lrow;
#pragma unroll
            for (int r = 0; r < 4; ++r) {
                int m = bmt * 128 + wy * 64 + im * 16 + quad * 4 + r;
                wei[(size_t)(c * 1152 + m) * ND + d] = f2b(acc[im][in][r]);
            }
        }
}

// ---------------------------------------------------------------------------
// Main MFMA GEMM with fused epilogues (see round 2), + source-swizzled LDS.
// ---------------------------------------------------------------------------
template <int MODE, int MINW>
__global__ __launch_bounds__(256, MINW) void k_gemm(
    const unsigned short* __restrict__ A, const unsigned short* __restrict__ B1,
    const unsigned short* __restrict__ B2, const float* __restrict__ bias1,
    const float* __restrict__ bias2, const float* __restrict__ rgnf,
    void* __restrict__ outp)
{
    const int K = ND;
    int bn = blockIdx.x, bm = blockIdx.y;
    int m0 = bm * BM, n0 = bn * BN;

    __shared__ __align__(16) unsigned short At[BM * BK];
    __shared__ __align__(16) unsigned short Bt[BN * BK];
    __shared__ __align__(16) unsigned short Bt2[MODE == 0 ? BN * BK : 16];

    int t = threadIdx.x;
    int lane = t & 63, wid = t >> 6;
    int wx = wid & 1, wy = wid >> 1;
    int lrow = lane & 15, quad = lane >> 4;

    floatx4 acc[4][4] = {};
    floatx4 acc2[MODE == 0 ? 4 : 1][MODE == 0 ? 4 : 1] = {};

    int srow = t >> 2;                              // 0..63
    int pos = t & 3;
    int ssw = (pos ^ ((srow >> 1) & 3)) * 8;        // swizzled source k-offset
    const unsigned short* Aptr  = A  + (size_t)(m0 + srow) * K + ssw;
    const unsigned short* B1ptr = B1 + (size_t)(n0 + srow) * K + ssw;
    const unsigned short* B2ptr = (MODE == 0) ? B2 + (size_t)(n0 + srow) * K + ssw : nullptr;
    unsigned short* Al  = &At[srow * BK + pos * 8];  // lane-linear dest
    unsigned short* Al2 = &At[(srow + 64) * BK + pos * 8];
    unsigned short* Bl  = &Bt[srow * BK + pos * 8];
    unsigned short* Bl2 = &Bt[(srow + 64) * BK + pos * 8];

    int fsw = (quad ^ ((lrow >> 1) & 3)) * 8;       // swizzled frag k-offset

    for (int kt = 0; kt < K; kt += BK) {
        gload16(Aptr + kt, Al);
        gload16(Aptr + (size_t)64 * K + kt, Al2);
        gload16(B1ptr + kt, Bl);
        gload16(B1ptr + (size_t)64 * K + kt, Bl2);
        if constexpr (MODE == 0) {
            gload16(B2ptr + kt, &Bt2[srow * BK + pos * 8]);
            gload16(B2ptr + (size_t)64 * K + kt, &Bt2[(srow + 64) * BK + pos * 8]);
        }
        __syncthreads();

        bf16x8 af[4], bfr[4];
#pragma unroll
        for (int im = 0; im < 4; ++im)
            af[im] = *(const bf16x8*)&At[(wy * 64 + im * 16 + lrow) * BK + fsw];
#pragma unroll
        for (int in = 0; in < 4; ++in)
            bfr[in] = *(const bf16x8*)&Bt[(wx * 64 + in * 16 + lrow) * BK + fsw];
#pragma unroll
        for (int im = 0; im < 4; ++im)
#pragma unroll
            for (int in = 0; in < 4; ++in)
                acc[im][in] = __builtin_amdgcn_mfma_f32_16x16x32_bf16(
                    af[im], bfr[in], acc[im][in], 0, 0, 0);
        if constexpr (MODE == 0) {
            bf16x8 bfr2[4];
#pragma unroll
            for (int in = 0; in < 4; ++in)
                bfr2[in] = *(const bf16x8*)&Bt2[(wx * 64 + in * 16 + lrow) * BK + fsw];
#pragma unroll
            for (int im = 0; im < 4; ++im)
#pragma unroll
                for (int in = 0; in < 4; ++in)
                    acc2[im][in] = __builtin_amdgcn_mfma_f32_16x16x32_bf16(
                        af[im], bfr2[in], acc2[im][in], 0, 0, 0);
        }
        __syncthreads();
    }

    // epilogue: C/D layout col = lane&15, row = quad*4 + reg  [m89/m91]
#pragma unroll
    for (int im = 0; im < 4; ++im) {
#pragma unroll
        for (int in = 0; in < 4; ++in) {
            int n = n0 + wx * 64 + in * 16 + lrow;
            float b1v = bias1[n];
            float b2v = (MODE == 0) ? bias2[n] : 0.f;
#pragma unroll
            for (int r = 0; r < 4; ++r) {
                int m = m0 + wy * 64 + im * 16 + quad * 4 + r;
                int q = m % NQ;
                int ci = m / NQ;
                int i = ci % NI, c = ci / NI;
                float v = acc[im][in][r];
                if constexpr (MODE == 0) {
                    float sc = tanhf(v + b1v);
                    float sh = acc2[im][in][r] + b2v;
                    float rg = rgnf[(size_t)(i * NQ + q) * ND + n];
                    ((unsigned short*)outp)[(size_t)m * ND + n] = f2b(rg * sc + sh);
                } else if constexpr (MODE == 1) {
                    float h = v + b1v;
                    ((unsigned short*)outp)[(size_t)m * ND + n] = f2b(h > 0.f ? h : 0.f);
                } else {
                    float rg = rgnf[(size_t)(i * NQ + q) * ND + n];
                    ((float*)outp)[((size_t)(i * NC + c) * NQ + q) * ND + n] = v + b1v + rg;
                }
            }
        }
    }
}

extern "C" void kernel_launch(void* const* d_in, const int* in_sizes, int n_in,
                              void* d_out, int out_size, void* d_ws, size_t ws_size,
                              hipStream_t stream) {
    const float* rgn     = (const float*)d_in[0];
    const float* wrd     = (const float*)d_in[2];
    const int*   lens    = (const int*)d_in[4];
    const float* w_scale = (const float*)d_in[5];
    const float* b_scale = (const float*)d_in[6];
    const float* w_shift = (const float*)d_in[7];
    const float* b_shift = (const float*)d_in[8];
    const float* w1      = (const float*)d_in[9];
    const float* b1      = (const float*)d_in[10];
    const float* w2      = (const float*)d_in[11];
    const float* b2      = (const float*)d_in[12];
    float* outf = (float*)d_out;

    // workspace layout (bytes):
    //   0         wsc_bf  2,097,152
    //   2097152   wsh_bf  2,097,152
    //   4194304   w1_bf   2,097,152
    //   6291456   w2_bf   2,097,152
    //   8388608   wrd_t   4,194,304   [c][d][l64] bf16
    //  12582912   attn    4,718,592   [c][i][q][l64] bf16
    //  17301504   wei    75,497,472   [c*1152+m][d] bf16  (also hbuf)
    //  hi/lo scratch aliased INSIDE wei region (dead before wei written):
    //  17301504   wrd_hi  3,305,472 (incl 14-row pad)
    //  20606976   wrd_lo  3,305,472
    //  23912448   rgn_hi  2,383,872 (incl 12-row pad)
    //  26296320   rgn_lo  2,383,872
    char* ws = (char*)d_ws;
    unsigned short* wsc_bf = (unsigned short*)(ws + 0);
    unsigned short* wsh_bf = (unsigned short*)(ws + 2097152);
    unsigned short* w1_bf  = (unsigned short*)(ws + 4194304);
    unsigned short* w2_bf  = (unsigned short*)(ws + 6291456);
    unsigned short* wrd_t  = (unsigned short*)(ws + 8388608);
    unsigned short* attn   = (unsigned short*)(ws + 12582912);
    unsigned short* wei    = (unsigned short*)(ws + 17301504);
    unsigned short* wrd_hi = (unsigned short*)(ws + 17301504);
    unsigned short* wrd_lo = (unsigned short*)(ws + 20606976);
    unsigned short* rgn_hi = (unsigned short*)(ws + 23912448);
    unsigned short* rgn_lo = (unsigned short*)(ws + 26296320);
    unsigned short* hbuf   = wei;                    // reuse after gemm<0>
    unsigned short* xbuf   = (unsigned short*)d_out; // bf16 x inside fp32 out buf

    CvtJobs jobs;
    jobs.j[0] = { w_scale, wsc_bf, ND * ND / 2 };
    jobs.j[1] = { w_shift, wsh_bf, ND * ND / 2 };
    jobs.j[2] = { w1,      w1_bf,  ND * ND / 2 };
    jobs.j[3] = { w2,      w2_bf,  ND * ND / 2 };
    k_cvt<<<dim3(128, 4), 256, 0, stream>>>(jobs);

    HlJobs hjobs;
    hjobs.j[0] = { wrd, wrd_hi, wrd_lo, NC * NL * ND / 2 };
    hjobs.j[1] = { rgn, rgn_hi, rgn_lo, NI * NQ * ND / 2 };
    k_cvt_hilo<<<dim3(128, 2), 256, 0, stream>>>(hjobs);

    k_cvt_t<<<dim3(4, 32), 256, 0, stream>>>(wrd, wrd_t);

    k_attn<<<NC * NI, 256, 0, stream>>>(wrd_hi, wrd_lo, rgn_hi, rgn_lo, lens, attn);

    k_wei_gemm<<<dim3(8, 9, 32), 256, 0, stream>>>(attn, wrd_t, wei);

    dim3 g(ND / BN, (NC * NI * NQ) / BM);  // 8 x 288
    k_gemm<0, 2><<<g, 256, 0, stream>>>(wei, wsc_bf, wsh_bf, b_scale, b_shift, rgn, xbuf);
    k_gemm<1, 2><<<g, 256, 0, stream>>>(xbuf, w1_bf, nullptr, b1, nullptr, rgn, hbuf);
    k_gemm<2, 2><<<g, 256, 0, stream>>>(hbuf, w2_bf, nullptr, b2, nullptr, rgn, outf);
}

// Round 5
// 562.444 us; speedup vs baseline: 2.2404x; 1.2704x over previous
//
#include <hip/hip_runtime.h>
#include <math.h>

#define NC 32
#define NI 32
#define NL 50
#define NQ 36
#define ND 1024
#define LAMBDA 9.0f

#define BM 128
#define BN 128
#define BK 32

typedef __attribute__((ext_vector_type(8))) short bf16x8;
typedef __attribute__((ext_vector_type(4))) float floatx4;

static __device__ __forceinline__ unsigned short f2b(float f) {
    unsigned int u = __float_as_uint(f);
    unsigned int r = (u + 0x7fffu + ((u >> 16) & 1u)) >> 16;  // RNE
    return (unsigned short)r;
}
static __device__ __forceinline__ float bf2f(unsigned short u) {
    return __uint_as_float(((unsigned int)u) << 16);
}

// async global->LDS, 16B/lane; LDS dest must be wave-uniform base + lane*16
static __device__ __forceinline__ void gload16(const unsigned short* g, unsigned short* l) {
    __builtin_amdgcn_global_load_lds(
        (const __attribute__((address_space(1))) unsigned int*)g,
        (__attribute__((address_space(3))) unsigned int*)l, 16, 0, 0);
}

// ---------------------------------------------------------------------------
// K0a: fp32 -> bf16 (4 weights + zero-padded wrd)
// ---------------------------------------------------------------------------
struct CvtJob { const float* src; unsigned short* dst; int n2; int valid2; };
struct CvtJobs { CvtJob j[5]; };

__global__ __launch_bounds__(256) void k_cvt(CvtJobs jobs) {
    CvtJob jb = jobs.j[blockIdx.y];
    unsigned int* d32 = (unsigned int*)jb.dst;
    int stride = gridDim.x * 256;
    for (int i = blockIdx.x * 256 + threadIdx.x; i < jb.n2; i += stride) {
        unsigned int pk = 0;
        if (i < jb.valid2) {
            float2 v = ((const float2*)jb.src)[i];
            pk = (unsigned int)f2b(v.x) | ((unsigned int)f2b(v.y) << 16);
        }
        d32[i] = pk;
    }
}

// ---------------------------------------------------------------------------
// K0b: fp32 -> bf16 hi/lo split (x ~= hi + lo, lo = bf16(x - hi))
// ---------------------------------------------------------------------------
struct HlJob { const float* src; unsigned short* hi; unsigned short* lo; int n2; };
struct HlJobs { HlJob j[2]; };

__global__ __launch_bounds__(256) void k_cvt_hilo(HlJobs jobs) {
    HlJob jb = jobs.j[blockIdx.y];
    unsigned int* h32 = (unsigned int*)jb.hi;
    unsigned int* l32 = (unsigned int*)jb.lo;
    int stride = gridDim.x * 256;
    for (int i = blockIdx.x * 256 + threadIdx.x; i < jb.n2; i += stride) {
        float2 v = ((const float2*)jb.src)[i];
        unsigned short h0 = f2b(v.x), h1 = f2b(v.y);
        unsigned short l0 = f2b(v.x - bf2f(h0)), l1 = f2b(v.y - bf2f(h1));
        h32[i] = (unsigned int)h0 | ((unsigned int)h1 << 16);
        l32[i] = (unsigned int)l0 | ((unsigned int)l1 << 16);
    }
}

// ---------------------------------------------------------------------------
// K1: fused scores+normalize+softmax. Block per (c,i).
// S = leaky(W.R^T) via bf16 hi/lo MFMA (fp32-class precision), L2-norm over q,
// masked softmax over l -> attn bf16 [c][i][q][l64] (zeros for l>=len).
// ---------------------------------------------------------------------------
#define SST 37  // S LDS col stride

__global__ __launch_bounds__(256) void k_attn(
    const unsigned short* __restrict__ whi, const unsigned short* __restrict__ wlo,
    const unsigned short* __restrict__ rhi, const unsigned short* __restrict__ rlo,
    const int* __restrict__ lens, unsigned short* __restrict__ attn)
{
    int bx = blockIdx.x;
    int c = bx / NI, i = bx % NI;
    __shared__ __align__(16) unsigned short Wh[64 * 32], Wl[64 * 32];
    __shared__ __align__(16) unsigned short Rh[48 * 32], Rl[48 * 32];
    __shared__ float S[64 * SST];
    int t = threadIdx.x, lane = t & 63, wid = t >> 6;
    int lrow = lane & 15, quad = lane >> 4;
    int len = lens[c];

    // staging: wave0->Wh, wave1->Wl, wave2->Rh, wave3->Rl
    int grow = lane >> 2;                            // row within 16-row group
    int ssw = ((lane & 3) ^ ((lane >> 3) & 3)) * 8;  // swizzled source chunk
    const unsigned short* garr = (wid == 0) ? whi : (wid == 1) ? wlo : (wid == 2) ? rhi : rlo;
    unsigned short* larr = (wid == 0) ? Wh : (wid == 1) ? Wl : (wid == 2) ? Rh : Rl;
    int ngroups = (wid < 2) ? 4 : 3;
    size_t gbase = (wid < 2) ? (size_t)(c * NL) * ND : (size_t)(i * NQ) * ND;

    floatx4 acc[3] = {};
    int fsw = (quad ^ ((lrow >> 1) & 3)) * 8;

    for (int kt = 0; kt < ND; kt += 32) {
        for (int j = 0; j < ngroups; ++j) {
            int row = j * 16 + grow;
            gload16(garr + gbase + (size_t)row * ND + kt + ssw, larr + j * 512 + lane * 8);
        }
        __syncthreads();
        bf16x8 ah = *(const bf16x8*)&Wh[(wid * 16 + lrow) * 32 + fsw];
        bf16x8 al = *(const bf16x8*)&Wl[(wid * 16 + lrow) * 32 + fsw];
#pragma unroll
        for (int nt = 0; nt < 3; ++nt) {
            bf16x8 bh = *(const bf16x8*)&Rh[(nt * 16 + lrow) * 32 + fsw];
            bf16x8 bl = *(const bf16x8*)&Rl[(nt * 16 + lrow) * 32 + fsw];
            acc[nt] = __builtin_amdgcn_mfma_f32_16x16x32_bf16(ah, bh, acc[nt], 0, 0, 0);
            acc[nt] = __builtin_amdgcn_mfma_f32_16x16x32_bf16(ah, bl, acc[nt], 0, 0, 0);
            acc[nt] = __builtin_amdgcn_mfma_f32_16x16x32_bf16(al, bh, acc[nt], 0, 0, 0);
        }
        __syncthreads();
    }
    // scatter to S: l = wid*16 + quad*4 + r, q = nt*16 + lrow
#pragma unroll
    for (int nt = 0; nt < 3; ++nt) {
        int q = nt * 16 + lrow;
        if (q < NQ) {
#pragma unroll
            for (int r = 0; r < 4; ++r) {
                int l = wid * 16 + quad * 4 + r;
                S[l * SST + q] = acc[nt][r];
            }
        }
    }
    __syncthreads();
    // leaky + L2-normalize over q, times lambda -> logits
    if (t < NL) {
        float lv[NQ];
        float ss = 0.f;
#pragma unroll
        for (int q = 0; q < NQ; ++q) {
            float v = S[t * SST + q];
            float x = (v >= 0.f) ? v : 0.1f * v;
            lv[q] = x;
            ss += x * x;
        }
        float inv = LAMBDA / fmaxf(sqrtf(ss), 1e-12f);
#pragma unroll
        for (int q = 0; q < NQ; ++q) S[t * SST + q] = lv[q] * inv;
    }
    __syncthreads();
    // masked softmax over l, emit attn bf16 [c][i][q][64]
    if (t < NQ) {
        int q = t;
        float m = -1e30f;
        for (int l = 0; l < len; ++l) m = fmaxf(m, S[l * SST + q]);
        float sum = 0.f;
        for (int l = 0; l < len; ++l) {
            float p = __expf(S[l * SST + q] - m);
            S[l * SST + q] = p;
            sum += p;
        }
        float inv = 1.f / sum;
        unsigned int* o = (unsigned int*)attn + ((size_t)(c * NI + i) * NQ + q) * 32;
        for (int j = 0; j < 32; ++j) {
            int l0 = 2 * j, l1 = 2 * j + 1;
            unsigned short a0 = (l0 < len) ? f2b(S[l0 * SST + q] * inv) : (unsigned short)0;
            unsigned short a1 = (l1 < len) ? f2b(S[l1 * SST + q] * inv) : (unsigned short)0;
            o[j] = (unsigned int)a0 | ((unsigned int)a1 << 16);
        }
    }
}

// ---------------------------------------------------------------------------
// K2: P_t[c][n][l64] = wrd_pad(1664xK) . W(NxK)^T, transposed scatter store.
// Standard 128x128xBK32 MFMA K-loop; grid.z selects (W, dst) pair.
// ---------------------------------------------------------------------------
__global__ __launch_bounds__(256, 2) void k_pgemm(
    const unsigned short* __restrict__ A, const unsigned short* __restrict__ B1,
    const unsigned short* __restrict__ B2, unsigned short* __restrict__ P1,
    unsigned short* __restrict__ P2)
{
    const int K = ND;
    int bn = blockIdx.x, bm = blockIdx.y;
    const unsigned short* B = blockIdx.z ? B2 : B1;
    unsigned short* P = blockIdx.z ? P2 : P1;
    int m0 = bm * BM, n0 = bn * BN;

    __shared__ __align__(16) unsigned short At[BM * BK];
    __shared__ __align__(16) unsigned short Bt[BN * BK];

    int t = threadIdx.x, lane = t & 63, wid = t >> 6;
    int wx = wid & 1, wy = wid >> 1;
    int lrow = lane & 15, quad = lane >> 4;
    floatx4 acc[4][4] = {};

    int srow = t >> 2, pos = t & 3;
    int ssw = (pos ^ ((srow >> 1) & 3)) * 8;
    const unsigned short* Aptr = A + (size_t)(m0 + srow) * K + ssw;
    const unsigned short* Bptr = B + (size_t)(n0 + srow) * K + ssw;
    unsigned short* Al  = &At[srow * BK + pos * 8];
    unsigned short* Al2 = &At[(srow + 64) * BK + pos * 8];
    unsigned short* Bl  = &Bt[srow * BK + pos * 8];
    unsigned short* Bl2 = &Bt[(srow + 64) * BK + pos * 8];
    int fsw = (quad ^ ((lrow >> 1) & 3)) * 8;

    for (int kt = 0; kt < K; kt += BK) {
        gload16(Aptr + kt, Al);
        gload16(Aptr + (size_t)64 * K + kt, Al2);
        gload16(Bptr + kt, Bl);
        gload16(Bptr + (size_t)64 * K + kt, Bl2);
        __syncthreads();
        bf16x8 af[4], bfr[4];
#pragma unroll
        for (int im = 0; im < 4; ++im)
            af[im] = *(const bf16x8*)&At[(wy * 64 + im * 16 + lrow) * BK + fsw];
#pragma unroll
        for (int in = 0; in < 4; ++in)
            bfr[in] = *(const bf16x8*)&Bt[(wx * 64 + in * 16 + lrow) * BK + fsw];
#pragma unroll
        for (int im = 0; im < 4; ++im)
#pragma unroll
            for (int in = 0; in < 4; ++in)
                acc[im][in] = __builtin_amdgcn_mfma_f32_16x16x32_bf16(
                    af[im], bfr[in], acc[im][in], 0, 0, 0);
        __syncthreads();
    }
    // transposed scatter: row m -> (c = m/50, l = m%50); store P[c][n][l]
#pragma unroll
    for (int im = 0; im < 4; ++im)
#pragma unroll
        for (int in = 0; in < 4; ++in) {
            int n = n0 + wx * 64 + in * 16 + lrow;
#pragma unroll
            for (int r = 0; r < 4; ++r) {
                int m = m0 + wy * 64 + im * 16 + quad * 4 + r;
                int c = m / NL, l = m - c * NL;
                if (c < NC) P[((size_t)(c * ND + n)) * 64 + l] = f2b(acc[im][in][r]);
            }
        }
}

// ---------------------------------------------------------------------------
// K3: batched K=64 dual GEMM + FiLM epilogue.
// sc = tanh(attn_c . P_sc[c] + b_sc), sh = attn_c . P_sh[c] + b_sh
// x[(c,m),n] = rgn[i,q,n]*sc + sh   (bf16), m = i*NQ+q
// ---------------------------------------------------------------------------
__global__ __launch_bounds__(256, 2) void k_attn_gemm(
    const unsigned short* __restrict__ attn, const unsigned short* __restrict__ Psc,
    const unsigned short* __restrict__ Psh, const float* __restrict__ bsc,
    const float* __restrict__ bsh, const float* __restrict__ rgnf,
    unsigned short* __restrict__ xbuf)
{
    int bn = blockIdx.x, bm = blockIdx.y, c = blockIdx.z;
    __shared__ __align__(16) unsigned short At[128 * 64], B1t[128 * 64], B2t[128 * 64];
    int t = threadIdx.x, lane = t & 63, wid = t >> 6;
    int wx = wid & 1, wy = wid >> 1;
    int lrow = lane & 15, quad = lane >> 4;
    int grow = lane >> 3, pos = lane & 7;

    const unsigned short* Ab  = attn + (size_t)(c * 1152 + bm * 128) * 64;
    const unsigned short* B1b = Psc + (size_t)(c * ND + bn * 128) * 64;
    const unsigned short* B2b = Psh + (size_t)(c * ND + bn * 128) * 64;
    for (int g = wid; g < 16; g += 4) {
        int row = g * 8 + grow;
        int ssw = (pos ^ (row & 7)) * 8;
        gload16(Ab + (size_t)row * 64 + ssw, &At[g * 512 + lane * 8]);
        gload16(B1b + (size_t)row * 64 + ssw, &B1t[g * 512 + lane * 8]);
        gload16(B2b + (size_t)row * 64 + ssw, &B2t[g * 512 + lane * 8]);
    }
    __syncthreads();

    floatx4 acc[4][4] = {}, acc2[4][4] = {};
#pragma unroll
    for (int kk = 0; kk < 2; ++kk) {
        int sw = ((kk * 4 + quad) ^ (lrow & 7)) * 8;
        bf16x8 af[4], b1f[4], b2f[4];
#pragma unroll
        for (int im = 0; im < 4; ++im)
            af[im] = *(const bf16x8*)&At[(wy * 64 + im * 16 + lrow) * 64 + sw];
#pragma unroll
        for (int in = 0; in < 4; ++in) {
            b1f[in] = *(const bf16x8*)&B1t[(wx * 64 + in * 16 + lrow) * 64 + sw];
            b2f[in] = *(const bf16x8*)&B2t[(wx * 64 + in * 16 + lrow) * 64 + sw];
        }
#pragma unroll
        for (int im = 0; im < 4; ++im)
#pragma unroll
            for (int in = 0; in < 4; ++in) {
                acc[im][in] = __builtin_amdgcn_mfma_f32_16x16x32_bf16(
                    af[im], b1f[in], acc[im][in], 0, 0, 0);
                acc2[im][in] = __builtin_amdgcn_mfma_f32_16x16x32_bf16(
                    af[im], b2f[in], acc2[im][in], 0, 0, 0);
            }
    }
#pragma unroll
    for (int im = 0; im < 4; ++im)
#pragma unroll
        for (int in = 0; in < 4; ++in) {
            int n = bn * 128 + wx * 64 + in * 16 + lrow;
            float b1v = bsc[n], b2v = bsh[n];
#pragma unroll
            for (int r = 0; r < 4; ++r) {
                int m = bm * 128 + wy * 64 + im * 16 + quad * 4 + r;  // < 1152
                int i = m / NQ, q = m - i * NQ;
                float sc = tanhf(acc[im][in][r] + b1v);
                float sh = acc2[im][in][r] + b2v;
                float rg = rgnf[(size_t)(i * NQ + q) * ND + n];
                xbuf[((size_t)(c * 1152 + m)) * ND + n] = f2b(rg * sc + sh);
            }
        }
}

// ---------------------------------------------------------------------------
// Main MFMA GEMM with fused epilogues + source-swizzled LDS.
// MODE 1: h = relu(A.B1^T + b1)  (bf16)
// MODE 2: out[(i,c,q),n] = A.B1^T + b1 + rgn  (fp32, c<->i permuted store)
// ---------------------------------------------------------------------------
template <int MODE, int MINW>
__global__ __launch_bounds__(256, MINW) void k_gemm(
    const unsigned short* __restrict__ A, const unsigned short* __restrict__ B1,
    const float* __restrict__ bias1, const float* __restrict__ rgnf,
    void* __restrict__ outp)
{
    const int K = ND;
    int bn = blockIdx.x, bm = blockIdx.y;
    int m0 = bm * BM, n0 = bn * BN;

    __shared__ __align__(16) unsigned short At[BM * BK];
    __shared__ __align__(16) unsigned short Bt[BN * BK];

    int t = threadIdx.x;
    int lane = t & 63, wid = t >> 6;
    int wx = wid & 1, wy = wid >> 1;
    int lrow = lane & 15, quad = lane >> 4;

    floatx4 acc[4][4] = {};

    int srow = t >> 2, pos = t & 3;
    int ssw = (pos ^ ((srow >> 1) & 3)) * 8;
    const unsigned short* Aptr  = A  + (size_t)(m0 + srow) * K + ssw;
    const unsigned short* B1ptr = B1 + (size_t)(n0 + srow) * K + ssw;
    unsigned short* Al  = &At[srow * BK + pos * 8];
    unsigned short* Al2 = &At[(srow + 64) * BK + pos * 8];
    unsigned short* Bl  = &Bt[srow * BK + pos * 8];
    unsigned short* Bl2 = &Bt[(srow + 64) * BK + pos * 8];
    int fsw = (quad ^ ((lrow >> 1) & 3)) * 8;

    for (int kt = 0; kt < K; kt += BK) {
        gload16(Aptr + kt, Al);
        gload16(Aptr + (size_t)64 * K + kt, Al2);
        gload16(B1ptr + kt, Bl);
        gload16(B1ptr + (size_t)64 * K + kt, Bl2);
        __syncthreads();

        bf16x8 af[4], bfr[4];
#pragma unroll
        for (int im = 0; im < 4; ++im)
            af[im] = *(const bf16x8*)&At[(wy * 64 + im * 16 + lrow) * BK + fsw];
#pragma unroll
        for (int in = 0; in < 4; ++in)
            bfr[in] = *(const bf16x8*)&Bt[(wx * 64 + in * 16 + lrow) * BK + fsw];
#pragma unroll
        for (int im = 0; im < 4; ++im)
#pragma unroll
            for (int in = 0; in < 4; ++in)
                acc[im][in] = __builtin_amdgcn_mfma_f32_16x16x32_bf16(
                    af[im], bfr[in], acc[im][in], 0, 0, 0);
        __syncthreads();
    }

    // epilogue: C/D layout col = lane&15, row = quad*4 + reg  [m89/m91]
#pragma unroll
    for (int im = 0; im < 4; ++im) {
#pragma unroll
        for (int in = 0; in < 4; ++in) {
            int n = n0 + wx * 64 + in * 16 + lrow;
            float b1v = bias1[n];
#pragma unroll
            for (int r = 0; r < 4; ++r) {
                int m = m0 + wy * 64 + im * 16 + quad * 4 + r;
                int q = m % NQ;
                int ci = m / NQ;
                int i = ci % NI, c = ci / NI;
                float v = acc[im][in][r];
                if constexpr (MODE == 1) {
                    float h = v + b1v;
                    ((unsigned short*)outp)[(size_t)m * ND + n] = f2b(h > 0.f ? h : 0.f);
                } else {
                    float rg = rgnf[(size_t)(i * NQ + q) * ND + n];
                    ((float*)outp)[((size_t)(i * NC + c) * NQ + q) * ND + n] = v + b1v + rg;
                }
            }
        }
    }
}

extern "C" void kernel_launch(void* const* d_in, const int* in_sizes, int n_in,
                              void* d_out, int out_size, void* d_ws, size_t ws_size,
                              hipStream_t stream) {
    const float* rgn     = (const float*)d_in[0];
    const float* wrd     = (const float*)d_in[2];
    const int*   lens    = (const int*)d_in[4];
    const float* w_scale = (const float*)d_in[5];
    const float* b_scale = (const float*)d_in[6];
    const float* w_shift = (const float*)d_in[7];
    const float* b_shift = (const float*)d_in[8];
    const float* w1      = (const float*)d_in[9];
    const float* b1      = (const float*)d_in[10];
    const float* w2      = (const float*)d_in[11];
    const float* b2      = (const float*)d_in[12];
    float* outf = (float*)d_out;

    // workspace layout (bytes):
    //   0         wsc_bf   2,097,152
    //   2097152   wsh_bf   2,097,152
    //   4194304   w1_bf    2,097,152
    //   6291456   w2_bf    2,097,152
    //   8388608   wrd_bf   3,407,872  (1664x1024, rows>=1600 zeroed) [dead after pgemm]
    //  11796480   attn     4,718,592  [c][i][q][l64]               [dead after attn_gemm]
    //  16515072   P_sct    4,194,304  [c][n][l64]                  [dead after attn_gemm]
    //  20709376   P_sht    4,194,304                               [dead after attn_gemm]
    //  24903680   wrd_hi   3,305,472  (incl 14-row pad)            [dead after k_attn]
    //  28209152   wrd_lo   3,305,472
    //  31514624   rgn_hi   2,383,872  (incl 12-row pad)
    //  33898496   rgn_lo   2,383,872   -> scratch ends 36,282,368
    //   8388608   hbuf    75,497,472  (gemm1 output; overlaps all-dead regions)
    char* ws = (char*)d_ws;
    unsigned short* wsc_bf = (unsigned short*)(ws + 0);
    unsigned short* wsh_bf = (unsigned short*)(ws + 2097152);
    unsigned short* w1_bf  = (unsigned short*)(ws + 4194304);
    unsigned short* w2_bf  = (unsigned short*)(ws + 6291456);
    unsigned short* wrd_bf = (unsigned short*)(ws + 8388608);
    unsigned short* attn   = (unsigned short*)(ws + 11796480);
    unsigned short* P_sct  = (unsigned short*)(ws + 16515072);
    unsigned short* P_sht  = (unsigned short*)(ws + 20709376);
    unsigned short* wrd_hi = (unsigned short*)(ws + 24903680);
    unsigned short* wrd_lo = (unsigned short*)(ws + 28209152);
    unsigned short* rgn_hi = (unsigned short*)(ws + 31514624);
    unsigned short* rgn_lo = (unsigned short*)(ws + 33898496);
    unsigned short* hbuf   = (unsigned short*)(ws + 8388608);
    unsigned short* xbuf   = (unsigned short*)d_out;  // bf16 x inside fp32 out buf

    CvtJobs jobs;
    jobs.j[0] = { w_scale, wsc_bf, ND * ND / 2, ND * ND / 2 };
    jobs.j[1] = { w_shift, wsh_bf, ND * ND / 2, ND * ND / 2 };
    jobs.j[2] = { w1,      w1_bf,  ND * ND / 2, ND * ND / 2 };
    jobs.j[3] = { w2,      w2_bf,  ND * ND / 2, ND * ND / 2 };
    jobs.j[4] = { wrd,     wrd_bf, 1664 * ND / 2, NC * NL * ND / 2 };
    k_cvt<<<dim3(128, 5), 256, 0, stream>>>(jobs);

    HlJobs hjobs;
    hjobs.j[0] = { wrd, wrd_hi, wrd_lo, NC * NL * ND / 2 };
    hjobs.j[1] = { rgn, rgn_hi, rgn_lo, NI * NQ * ND / 2 };
    k_cvt_hilo<<<dim3(128, 2), 256, 0, stream>>>(hjobs);

    k_attn<<<NC * NI, 256, 0, stream>>>(wrd_hi, wrd_lo, rgn_hi, rgn_lo, lens, attn);

    k_pgemm<<<dim3(8, 13, 2), 256, 0, stream>>>(wrd_bf, wsc_bf, wsh_bf, P_sct, P_sht);

    k_attn_gemm<<<dim3(8, 9, 32), 256, 0, stream>>>(attn, P_sct, P_sht,
                                                    b_scale, b_shift, rgn, xbuf);

    dim3 g(ND / BN, (NC * NI * NQ) / BM);  // 8 x 288
    k_gemm<1, 2><<<g, 256, 0, stream>>>(xbuf, w1_bf, b1, rgn, hbuf);
    k_gemm<2, 2><<<g, 256, 0, stream>>>(hbuf, w2_bf, b2, rgn, outf);
}